// Round 1
// baseline (1644.207 us; speedup 1.0000x reference)
//
#include <hip/hip_runtime.h>

// GCN 2-layer encoder for MI355X (gfx950).
// Pipeline per call (all on `stream`, graph-capture safe):
//   1. k_init      : deg[i]=1 (self loop), flag=1
//   2. k_detect64  : flag=0 if edge_index is int32 (odd dwords nonzero)
//   3. k_count     : deg[dst]++ over edges (int atomics)
//   4. k_dinv      : dinv[i] = rsqrt(deg[i])
//   5. k_gemm<128,false> : h1 = x @ W1           (fp32 VALU, LDS tiled)
//   6. k_selfbias<128>   : agg1 = h1*dinv^2 + b1 (self-loop + bias)
//   7. k_scatter<128>    : agg1[dst] += h1[src]*dinv[src]*dinv[dst]
//   8. k_gemm<64,true>   : h2 = relu(agg1) @ W2  (ReLU fused into load)
//   9. k_selfbias<64>    : out = h2*dinv^2 + b2
//  10. k_scatter<64>     : out[dst] += h2[src]*dinv[src]*dinv[dst]

constexpr int IN_CH = 128;
constexpr int HID   = 128;
constexpr int OUT_CH = 64;

__global__ void k_init(int* __restrict__ deg, int* __restrict__ flag, int N) {
    int i = blockIdx.x * blockDim.x + threadIdx.x;
    if (i == 0) *flag = 1;
    for (; i < N; i += gridDim.x * blockDim.x) deg[i] = 1;
}

// If edge_index is int64 (little-endian, values < 2^31), the first 2E dwords
// are E (lo,hi) pairs with hi==0. If int32, odd dwords hold real indices and
// the probability they are all zero is nil.
__global__ void k_detect64(const int* __restrict__ ei, int* __restrict__ flag, int E) {
    int i = blockIdx.x * blockDim.x + threadIdx.x;
    for (int j = i; j < E; j += gridDim.x * blockDim.x) {
        if (ei[2 * j + 1] != 0) *flag = 0;   // race-free: all writers store 0
    }
}

__device__ __forceinline__ void load_edge(const int* __restrict__ ei, int e, int E,
                                          bool is64, int& s, int& d) {
    if (is64) { s = ei[2 * e]; d = ei[2 * (E + e)]; }
    else      { s = ei[e];     d = ei[E + e]; }
}

__global__ void k_count(const int* __restrict__ ei, const int* __restrict__ flag,
                        int* __restrict__ deg, int E) {
    const bool is64 = (*flag != 0);
    int i = blockIdx.x * blockDim.x + threadIdx.x;
    for (int e = i; e < E; e += gridDim.x * blockDim.x) {
        int d = is64 ? ei[2 * (E + e)] : ei[E + e];
        atomicAdd(&deg[d], 1);
    }
}

__global__ void k_dinv(const int* __restrict__ deg, float* __restrict__ dinv, int N) {
    int i = blockIdx.x * blockDim.x + threadIdx.x;
    for (; i < N; i += gridDim.x * blockDim.x)
        dinv[i] = rsqrtf((float)deg[i]);
}

// Y[M x NC] = X[M x 128] @ W[128 x NC], optional ReLU applied to X on load.
// Block: 256 threads, 32 rows per block. W staged in 32-k chunks (16/8 KB),
// x tile staged once, padded to stride 132 to avoid LDS bank conflicts.
template <int NC, bool RELU>
__global__ __launch_bounds__(256) void k_gemm(const float* __restrict__ X,
                                              const float* __restrict__ W,
                                              float* __restrict__ Y, int M) {
    __shared__ float ws[32 * NC];
    __shared__ float xs[32][132];
    const int tid  = threadIdx.x;
    const int row0 = blockIdx.x * 32;

    // stage x tile (32 rows x 128 k), ReLU fused
    {
        const int c4 = tid & 31;   // float4 column 0..31
        const int rb = tid >> 5;   // 0..7
#pragma unroll
        for (int it = 0; it < 4; ++it) {
            int r  = rb + it * 8;
            int gr = row0 + r;
            float4 v = make_float4(0.f, 0.f, 0.f, 0.f);
            if (gr < M) v = reinterpret_cast<const float4*>(X + (size_t)gr * 128)[c4];
            if (RELU) {
                v.x = fmaxf(v.x, 0.f); v.y = fmaxf(v.y, 0.f);
                v.z = fmaxf(v.z, 0.f); v.w = fmaxf(v.w, 0.f);
            }
            *reinterpret_cast<float4*>(&xs[r][c4 * 4]) = v;
        }
    }

    constexpr int CPT = NC / 16;      // cols per thread (8 or 4)
    const int tx = tid & 15;          // col group
    const int ty = tid >> 4;          // 0..15 -> rows ty and ty+16
    float acc0[CPT] = {};
    float acc1[CPT] = {};

    for (int k0 = 0; k0 < 128; k0 += 32) {
        __syncthreads();  // xs ready (iter 0) / previous ws consumption done
        for (int i = tid; i < 32 * NC / 4; i += 256)
            reinterpret_cast<float4*>(ws)[i] =
                reinterpret_cast<const float4*>(W + (size_t)k0 * NC)[i];
        __syncthreads();
#pragma unroll
        for (int kk = 0; kk < 32; ++kk) {
            const float a0 = xs[ty][k0 + kk];
            const float a1 = xs[ty + 16][k0 + kk];
            const float* wk = &ws[kk * NC + tx * CPT];
#pragma unroll
            for (int j = 0; j < CPT; ++j) {
                acc0[j] = fmaf(a0, wk[j], acc0[j]);
                acc1[j] = fmaf(a1, wk[j], acc1[j]);
            }
        }
    }

    const int gr0 = row0 + ty, gr1 = row0 + ty + 16;
    if (gr0 < M) {
#pragma unroll
        for (int j = 0; j < CPT; ++j) Y[(size_t)gr0 * NC + tx * CPT + j] = acc0[j];
    }
    if (gr1 < M) {
#pragma unroll
        for (int j = 0; j < CPT; ++j) Y[(size_t)gr1 * NC + tx * CPT + j] = acc1[j];
    }
}

// out[i][c] = h[i][c]*dinv[i]^2 + b[c]  (self-loop message + bias)
template <int C>
__global__ void k_selfbias(const float* __restrict__ h, const float* __restrict__ dinv,
                           const float* __restrict__ b, float* __restrict__ out, int N) {
    constexpr int C4 = C / 4;
    const int total = N * C4;
    for (int i = blockIdx.x * blockDim.x + threadIdx.x; i < total;
         i += gridDim.x * blockDim.x) {
        const int node = i / C4;
        const int c4   = i % C4;
        float w = dinv[node];
        w *= w;
        float4 v  = reinterpret_cast<const float4*>(h)[i];
        float4 bb = reinterpret_cast<const float4*>(b)[c4];
        float4 o  = make_float4(fmaf(v.x, w, bb.x), fmaf(v.y, w, bb.y),
                                fmaf(v.z, w, bb.z), fmaf(v.w, w, bb.w));
        reinterpret_cast<float4*>(out)[i] = o;
    }
}

// agg[dst] += h[src] * dinv[src]*dinv[dst], C/4 lanes per edge, float4 gather.
template <int C>
__global__ void k_scatter(const float* __restrict__ h, const int* __restrict__ ei,
                          const int* __restrict__ flag, const float* __restrict__ dinv,
                          float* __restrict__ agg, int E) {
    constexpr int LPE = C / 4;  // lanes per edge (32 or 16)
    const bool is64 = (*flag != 0);
    const int gid  = blockIdx.x * blockDim.x + threadIdx.x;
    const int lane = gid & (LPE - 1);
    const int step = (gridDim.x * blockDim.x) / LPE;
    for (int e = gid / LPE; e < E; e += step) {
        int s, d;
        load_edge(ei, e, E, is64, s, d);
        const float w = dinv[s] * dinv[d];
        const float4 v = reinterpret_cast<const float4*>(h + (size_t)s * C)[lane];
        float* p = agg + (size_t)d * C + lane * 4;
        atomicAdd(p + 0, v.x * w);
        atomicAdd(p + 1, v.y * w);
        atomicAdd(p + 2, v.z * w);
        atomicAdd(p + 3, v.w * w);
    }
}

extern "C" void kernel_launch(void* const* d_in, const int* in_sizes, int n_in,
                              void* d_out, int out_size, void* d_ws, size_t ws_size,
                              hipStream_t stream) {
    const float* x  = (const float*)d_in[0];
    const int*   ei = (const int*)d_in[1];
    const float* W1 = (const float*)d_in[2];
    const float* b1 = (const float*)d_in[3];
    const float* W2 = (const float*)d_in[4];
    const float* b2 = (const float*)d_in[5];
    float* out = (float*)d_out;

    const int N = in_sizes[0] / IN_CH;   // 50000
    const int E = in_sizes[1] / 2;       // 600000

    // workspace carve-up (256B aligned)
    char* wsb = (char*)d_ws;
    size_t off = 0;
    auto alloc = [&](size_t bytes) -> void* {
        void* p = wsb + off;
        off += (bytes + 255) & ~(size_t)255;
        return p;
    };
    int*   deg  = (int*)alloc((size_t)N * sizeof(int));
    int*   flag = (int*)alloc(256);
    float* dinv = (float*)alloc((size_t)N * sizeof(float));
    float* h1   = (float*)alloc((size_t)N * HID * sizeof(float));
    float* agg1 = (float*)alloc((size_t)N * HID * sizeof(float));
    float* h2   = h1;  // h1 dead after scatter into agg1; reuse for layer-2 transform

    auto gs = [](long long n) { return (int)((n + 255) / 256); };

    k_init<<<gs(N), 256, 0, stream>>>(deg, flag, N);
    k_detect64<<<2048, 256, 0, stream>>>(ei, flag, E);
    k_count<<<gs(E), 256, 0, stream>>>(ei, flag, deg, E);
    k_dinv<<<gs(N), 256, 0, stream>>>(deg, dinv, N);

    // layer 1
    k_gemm<HID, false><<<(N + 31) / 32, 256, 0, stream>>>(x, W1, h1, N);
    k_selfbias<HID><<<min(gs((long long)N * HID / 4), 8192), 256, 0, stream>>>(
        h1, dinv, b1, agg1, N);
    k_scatter<HID><<<16384, 256, 0, stream>>>(h1, ei, flag, dinv, agg1, E);

    // layer 2 (ReLU fused into GEMM2 load)
    k_gemm<OUT_CH, true><<<(N + 31) / 32, 256, 0, stream>>>(agg1, W2, h2, N);
    k_selfbias<OUT_CH><<<min(gs((long long)N * OUT_CH / 4), 8192), 256, 0, stream>>>(
        h2, dinv, b2, out, N);
    k_scatter<OUT_CH><<<16384, 256, 0, stream>>>(h2, ei, flag, dinv, out, E);
}

// Round 2
// 254.009 us; speedup vs baseline: 6.4730x; 6.4730x over previous
//
#include <hip/hip_runtime.h>

// GCN 2-layer encoder for MI355X (gfx950) — round 2: atomic-free aggregation.
// Round-1 post-mortem: edge scatter with float atomics was 93% of runtime
// (75 G atomics/s rate-limit, VALUBusy 1.2%, HBM 17%). Replaced by on-device
// CSR (counting sort by dst) + per-node register gather-reduce.
//
// Pipeline (all on `stream`, graph-capture safe):
//   1. k_init        : deg[i]=1 (self loop), flag=1
//   2. k_detect64    : flag=0 if edge_index is int32
//   3. k_count       : deg[dst]++ (int atomics, 600k)
//   4. k_dinv        : dinv = rsqrt(deg)          [deg dead after this]
//   5. k_scan        : row_ptr/cursor = exclscan(deg-1)  [cursor aliases deg]
//   6. k_fill        : csr_src[atomicAdd(cursor[dst])] = src
//   7. k_gemm<128,false> : h1 = x @ W1
//   8. k_gather<128> : agg1[n] = b1 + h1[n]*dinv[n]^2 + sum_e h1[src]*dinv*dinv
//   9. k_gemm<64,true>   : h2 = relu(agg1) @ W2
//  10. k_gather<64>  : out = b2 + ...

constexpr int IN_CH  = 128;
constexpr int HID    = 128;
constexpr int OUT_CH = 64;

__global__ void k_init(int* __restrict__ deg, int* __restrict__ flag, int N) {
    int i = blockIdx.x * blockDim.x + threadIdx.x;
    if (i == 0) *flag = 1;
    for (; i < N; i += gridDim.x * blockDim.x) deg[i] = 1;
}

__global__ void k_detect64(const int* __restrict__ ei, int* __restrict__ flag, int E) {
    int i = blockIdx.x * blockDim.x + threadIdx.x;
    for (int j = i; j < E; j += gridDim.x * blockDim.x) {
        if (ei[2 * j + 1] != 0) *flag = 0;
    }
}

__device__ __forceinline__ void load_edge(const int* __restrict__ ei, int e, int E,
                                          bool is64, int& s, int& d) {
    if (is64) { s = ei[2 * e]; d = ei[2 * (E + e)]; }
    else      { s = ei[e];     d = ei[E + e]; }
}

__global__ void k_count(const int* __restrict__ ei, const int* __restrict__ flag,
                        int* __restrict__ deg, int E) {
    const bool is64 = (*flag != 0);
    int i = blockIdx.x * blockDim.x + threadIdx.x;
    for (int e = i; e < E; e += gridDim.x * blockDim.x) {
        int d = is64 ? ei[2 * (E + e)] : ei[E + e];
        atomicAdd(&deg[d], 1);
    }
}

__global__ void k_dinv(const int* __restrict__ deg, float* __restrict__ dinv, int N) {
    int i = blockIdx.x * blockDim.x + threadIdx.x;
    for (; i < N; i += gridDim.x * blockDim.x)
        dinv[i] = rsqrtf((float)deg[i]);
}

// Single-block exclusive scan of (deg[i]-1) -> row_ptr, cursor. 1024 threads,
// wave-shuffle scan (2-3 __syncthreads per 1024-chunk). row_ptr[N] = E.
// NOTE: cursor may alias deg (each i is read before written by the same thread).
__global__ __launch_bounds__(1024) void k_scan(const int* __restrict__ deg,
                                               int* __restrict__ row_ptr,
                                               int* __restrict__ cursor, int N) {
    __shared__ int wsum[16];
    __shared__ int carry_s;
    if (threadIdx.x == 0) carry_s = 0;
    __syncthreads();
    const int lane = threadIdx.x & 63;
    const int wid  = threadIdx.x >> 6;
    for (int base = 0; base < N; base += 1024) {
        const int i = base + threadIdx.x;
        const int v = (i < N) ? (deg[i] - 1) : 0;
        int incl = v;
#pragma unroll
        for (int off = 1; off < 64; off <<= 1) {
            int t = __shfl_up(incl, off, 64);
            if (lane >= off) incl += t;
        }
        if (lane == 63) wsum[wid] = incl;
        __syncthreads();
        int woff = 0;
#pragma unroll
        for (int w2 = 0; w2 < 16; ++w2) woff += (w2 < wid) ? wsum[w2] : 0;
        const int excl = carry_s + woff + incl - v;
        if (i < N) { row_ptr[i] = excl; cursor[i] = excl; }
        __syncthreads();
        if (threadIdx.x == 1023) carry_s += woff + incl;  // chunk total
        __syncthreads();
    }
    if (threadIdx.x == 0) row_ptr[N] = carry_s;
}

__global__ void k_fill(const int* __restrict__ ei, const int* __restrict__ flag,
                       int* __restrict__ cursor, int* __restrict__ csr_src, int E) {
    const bool is64 = (*flag != 0);
    int i = blockIdx.x * blockDim.x + threadIdx.x;
    for (int e = i; e < E; e += gridDim.x * blockDim.x) {
        int s, d;
        load_edge(ei, e, E, is64, s, d);
        const int pos = atomicAdd(&cursor[d], 1);
        csr_src[pos] = s;
    }
}

// Y[M x NC] = X[M x 128] @ W[128 x NC], optional ReLU applied to X on load.
template <int NC, bool RELU>
__global__ __launch_bounds__(256) void k_gemm(const float* __restrict__ X,
                                              const float* __restrict__ W,
                                              float* __restrict__ Y, int M) {
    __shared__ float ws[32 * NC];
    __shared__ float xs[32][132];
    const int tid  = threadIdx.x;
    const int row0 = blockIdx.x * 32;

    {
        const int c4 = tid & 31;
        const int rb = tid >> 5;
#pragma unroll
        for (int it = 0; it < 4; ++it) {
            int r  = rb + it * 8;
            int gr = row0 + r;
            float4 v = make_float4(0.f, 0.f, 0.f, 0.f);
            if (gr < M) v = reinterpret_cast<const float4*>(X + (size_t)gr * 128)[c4];
            if (RELU) {
                v.x = fmaxf(v.x, 0.f); v.y = fmaxf(v.y, 0.f);
                v.z = fmaxf(v.z, 0.f); v.w = fmaxf(v.w, 0.f);
            }
            *reinterpret_cast<float4*>(&xs[r][c4 * 4]) = v;
        }
    }

    constexpr int CPT = NC / 16;
    const int tx = tid & 15;
    const int ty = tid >> 4;
    float acc0[CPT] = {};
    float acc1[CPT] = {};

    for (int k0 = 0; k0 < 128; k0 += 32) {
        __syncthreads();
        for (int i = tid; i < 32 * NC / 4; i += 256)
            reinterpret_cast<float4*>(ws)[i] =
                reinterpret_cast<const float4*>(W + (size_t)k0 * NC)[i];
        __syncthreads();
#pragma unroll
        for (int kk = 0; kk < 32; ++kk) {
            const float a0 = xs[ty][k0 + kk];
            const float a1 = xs[ty + 16][k0 + kk];
            const float* wk = &ws[kk * NC + tx * CPT];
#pragma unroll
            for (int j = 0; j < CPT; ++j) {
                acc0[j] = fmaf(a0, wk[j], acc0[j]);
                acc1[j] = fmaf(a1, wk[j], acc1[j]);
            }
        }
    }

    const int gr0 = row0 + ty, gr1 = row0 + ty + 16;
    if (gr0 < M) {
#pragma unroll
        for (int j = 0; j < CPT; ++j) Y[(size_t)gr0 * NC + tx * CPT + j] = acc0[j];
    }
    if (gr1 < M) {
#pragma unroll
        for (int j = 0; j < CPT; ++j) Y[(size_t)gr1 * NC + tx * CPT + j] = acc1[j];
    }
}

// out[n] = b + h[n]*dinv[n]^2 + sum_{e in CSR[n]} h[src_e] * dinv[src_e]*dinv[n]
// C/4 lanes per node, float4 accumulation in registers; edges unrolled x2.
template <int C>
__global__ __launch_bounds__(256) void k_gather(const float* __restrict__ h,
                                                const int* __restrict__ row_ptr,
                                                const int* __restrict__ csr_src,
                                                const float* __restrict__ dinv,
                                                const float* __restrict__ b,
                                                float* __restrict__ out, int N) {
    constexpr int LPN = C / 4;  // lanes per node (32 or 16)
    const int tid  = blockIdx.x * blockDim.x + threadIdx.x;
    const int node = tid / LPN;
    const int lane = tid % LPN;
    if (node >= N) return;

    const float dn = dinv[node];
    float4 acc = reinterpret_cast<const float4*>(b)[lane];
    {
        const float w = dn * dn;  // self-loop weight
        const float4 v = reinterpret_cast<const float4*>(h + (size_t)node * C)[lane];
        acc.x = fmaf(v.x, w, acc.x); acc.y = fmaf(v.y, w, acc.y);
        acc.z = fmaf(v.z, w, acc.z); acc.w = fmaf(v.w, w, acc.w);
    }

    const int e1 = row_ptr[node + 1];
    int e = row_ptr[node];
    for (; e + 1 < e1; e += 2) {
        const int s0 = csr_src[e];
        const int s1 = csr_src[e + 1];
        const float w0 = dinv[s0] * dn;
        const float w1 = dinv[s1] * dn;
        const float4 v0 = reinterpret_cast<const float4*>(h + (size_t)s0 * C)[lane];
        const float4 v1 = reinterpret_cast<const float4*>(h + (size_t)s1 * C)[lane];
        acc.x = fmaf(v0.x, w0, acc.x); acc.y = fmaf(v0.y, w0, acc.y);
        acc.z = fmaf(v0.z, w0, acc.z); acc.w = fmaf(v0.w, w0, acc.w);
        acc.x = fmaf(v1.x, w1, acc.x); acc.y = fmaf(v1.y, w1, acc.y);
        acc.z = fmaf(v1.z, w1, acc.z); acc.w = fmaf(v1.w, w1, acc.w);
    }
    if (e < e1) {
        const int s0 = csr_src[e];
        const float w0 = dinv[s0] * dn;
        const float4 v0 = reinterpret_cast<const float4*>(h + (size_t)s0 * C)[lane];
        acc.x = fmaf(v0.x, w0, acc.x); acc.y = fmaf(v0.y, w0, acc.y);
        acc.z = fmaf(v0.z, w0, acc.z); acc.w = fmaf(v0.w, w0, acc.w);
    }

    reinterpret_cast<float4*>(out + (size_t)node * C)[lane] = acc;
}

extern "C" void kernel_launch(void* const* d_in, const int* in_sizes, int n_in,
                              void* d_out, int out_size, void* d_ws, size_t ws_size,
                              hipStream_t stream) {
    const float* x  = (const float*)d_in[0];
    const int*   ei = (const int*)d_in[1];
    const float* W1 = (const float*)d_in[2];
    const float* b1 = (const float*)d_in[3];
    const float* W2 = (const float*)d_in[4];
    const float* b2 = (const float*)d_in[5];
    float* out = (float*)d_out;

    const int N = in_sizes[0] / IN_CH;   // 50000
    const int E = in_sizes[1] / 2;       // 600000

    char* wsb = (char*)d_ws;
    size_t off = 0;
    auto alloc = [&](size_t bytes) -> void* {
        void* p = wsb + off;
        off += (bytes + 255) & ~(size_t)255;
        return p;
    };
    int*   deg     = (int*)alloc((size_t)N * sizeof(int));
    int*   flag    = (int*)alloc(256);
    float* dinv    = (float*)alloc((size_t)N * sizeof(float));
    int*   row_ptr = (int*)alloc(((size_t)N + 1) * sizeof(int));
    int*   csr_src = (int*)alloc((size_t)E * sizeof(int));
    float* h1      = (float*)alloc((size_t)N * HID * sizeof(float));
    float* agg1    = (float*)alloc((size_t)N * HID * sizeof(float));
    int*   cursor  = deg;   // deg dead after k_dinv; k_scan reads deg[i] before writing
    float* h2      = h1;    // h1 dead after gather1

    auto gs = [](long long n) { return (int)((n + 255) / 256); };

    k_init<<<gs(N), 256, 0, stream>>>(deg, flag, N);
    k_detect64<<<2048, 256, 0, stream>>>(ei, flag, E);
    k_count<<<gs(E), 256, 0, stream>>>(ei, flag, deg, E);
    k_dinv<<<gs(N), 256, 0, stream>>>(deg, dinv, N);
    k_scan<<<1, 1024, 0, stream>>>(deg, row_ptr, cursor, N);
    k_fill<<<gs(E), 256, 0, stream>>>(ei, flag, cursor, csr_src, E);

    // layer 1
    k_gemm<HID, false><<<(N + 31) / 32, 256, 0, stream>>>(x, W1, h1, N);
    k_gather<HID><<<gs((long long)N * (HID / 4)), 256, 0, stream>>>(
        h1, row_ptr, csr_src, dinv, b1, agg1, N);

    // layer 2 (ReLU fused into GEMM2 load)
    k_gemm<OUT_CH, true><<<(N + 31) / 32, 256, 0, stream>>>(agg1, W2, h2, N);
    k_gather<OUT_CH><<<gs((long long)N * (OUT_CH / 4)), 256, 0, stream>>>(
        h2, row_ptr, csr_src, dinv, b2, out, N);
}

// Round 3
// 223.676 us; speedup vs baseline: 7.3508x; 1.1356x over previous
//
#include <hip/hip_runtime.h>

// GCN 2-layer encoder for MI355X (gfx950) — round 3.
// r2 post-mortem: gemm<128> 50.7us (6.4M LDS bank conflicts, VALUBusy 25%),
// gather<128> 49.3us (307MB gathered at ~6.2TB/s mixed L3/HBM ceiling).
// r3: (a) h1/h2 stored as bf16 (only gathers consume them) -> gather bytes
// halved; per-edge weight dinv[src] precomputed into csr_w (kills 600k
// random 4B reads per gather). (b) GEMM rebuilt: 8rowsx4cols/thread, all
// LDS reads ds_read_b128, conflict-free layout; fp32 math unchanged.
//
// Pipeline: init -> detect64 -> count -> dinv -> scan -> fill(csr+w)
//   -> gemm<128>(x,W1)->h1b[bf16] -> gather<128>(h1b)+b1 -> agg1[f32]
//   -> gemm<64>(relu(agg1),W2)->h2b[bf16] -> gather<64>(h2b)+b2 -> out[f32]

constexpr int IN_CH  = 128;
constexpr int HID    = 128;
constexpr int OUT_CH = 64;

__device__ __forceinline__ unsigned short f2bf_rne(float f) {
    unsigned int u = __float_as_uint(f);
    u += 0x7FFFu + ((u >> 16) & 1u);
    return (unsigned short)(u >> 16);
}
__device__ __forceinline__ float bf2f(unsigned short h) {
    return __uint_as_float((unsigned int)h << 16);
}

__global__ void k_init(int* __restrict__ deg, int* __restrict__ flag, int N) {
    int i = blockIdx.x * blockDim.x + threadIdx.x;
    if (i == 0) *flag = 1;
    for (; i < N; i += gridDim.x * blockDim.x) deg[i] = 1;
}

__global__ void k_detect64(const int* __restrict__ ei, int* __restrict__ flag, int E) {
    int i = blockIdx.x * blockDim.x + threadIdx.x;
    for (int j = i; j < E; j += gridDim.x * blockDim.x) {
        if (ei[2 * j + 1] != 0) *flag = 0;
    }
}

__device__ __forceinline__ void load_edge(const int* __restrict__ ei, int e, int E,
                                          bool is64, int& s, int& d) {
    if (is64) { s = ei[2 * e]; d = ei[2 * (E + e)]; }
    else      { s = ei[e];     d = ei[E + e]; }
}

__global__ void k_count(const int* __restrict__ ei, const int* __restrict__ flag,
                        int* __restrict__ deg, int E) {
    const bool is64 = (*flag != 0);
    int i = blockIdx.x * blockDim.x + threadIdx.x;
    for (int e = i; e < E; e += gridDim.x * blockDim.x) {
        int d = is64 ? ei[2 * (E + e)] : ei[E + e];
        atomicAdd(&deg[d], 1);
    }
}

__global__ void k_dinv(const int* __restrict__ deg, float* __restrict__ dinv, int N) {
    int i = blockIdx.x * blockDim.x + threadIdx.x;
    for (; i < N; i += gridDim.x * blockDim.x)
        dinv[i] = rsqrtf((float)deg[i]);
}

// Single-block exclusive scan of (deg[i]-1) -> row_ptr, cursor. cursor may
// alias deg (each element read before written by the same thread).
__global__ __launch_bounds__(1024) void k_scan(const int* __restrict__ deg,
                                               int* __restrict__ row_ptr,
                                               int* __restrict__ cursor, int N) {
    __shared__ int wsum[16];
    __shared__ int carry_s;
    if (threadIdx.x == 0) carry_s = 0;
    __syncthreads();
    const int lane = threadIdx.x & 63;
    const int wid  = threadIdx.x >> 6;
    for (int base = 0; base < N; base += 1024) {
        const int i = base + threadIdx.x;
        const int v = (i < N) ? (deg[i] - 1) : 0;
        int incl = v;
#pragma unroll
        for (int off = 1; off < 64; off <<= 1) {
            int t = __shfl_up(incl, off, 64);
            if (lane >= off) incl += t;
        }
        if (lane == 63) wsum[wid] = incl;
        __syncthreads();
        int woff = 0;
#pragma unroll
        for (int w2 = 0; w2 < 16; ++w2) woff += (w2 < wid) ? wsum[w2] : 0;
        const int excl = carry_s + woff + incl - v;
        if (i < N) { row_ptr[i] = excl; cursor[i] = excl; }
        __syncthreads();
        if (threadIdx.x == 1023) carry_s += woff + incl;
        __syncthreads();
    }
    if (threadIdx.x == 0) row_ptr[N] = carry_s;
}

__global__ void k_fill(const int* __restrict__ ei, const int* __restrict__ flag,
                       const float* __restrict__ dinv, int* __restrict__ cursor,
                       int* __restrict__ csr_src, float* __restrict__ csr_w, int E) {
    const bool is64 = (*flag != 0);
    int i = blockIdx.x * blockDim.x + threadIdx.x;
    for (int e = i; e < E; e += gridDim.x * blockDim.x) {
        int s, d;
        load_edge(ei, e, E, is64, s, d);
        const int pos = atomicAdd(&cursor[d], 1);
        csr_src[pos] = s;
        csr_w[pos]   = dinv[s];
    }
}

// Y[M x NC](bf16) = X[M x 128](f32, optional ReLU) @ W[128 x NC](f32).
// 256 threads; COL4 = NC/4 col-groups; ROWT = 256/COL4 row-threads;
// 8 rows/thread -> tile TILE_R = 8*ROWT rows. K staged in 32-chunks.
// All LDS reads are ds_read_b128: ws at 16B lane stride (conflict-free),
// xs broadcast with rows ty + ROWT*j (ty-groups land on distinct banks).
template <int NC, bool RELU>
__global__ __launch_bounds__(256) void k_gemm(const float* __restrict__ X,
                                              const float* __restrict__ W,
                                              unsigned short* __restrict__ Y, int M) {
    constexpr int COL4   = NC / 4;        // 32 or 16
    constexpr int ROWT   = 256 / COL4;    // 8 or 16
    constexpr int TILE_R = 8 * ROWT;      // 64 or 128
    constexpr int XS_STRIDE = 36;         // floats; 144B, 16B-aligned

    __shared__ __align__(16) float ws[32 * NC];
    __shared__ __align__(16) float xs[TILE_R * XS_STRIDE];

    const int tid  = threadIdx.x;
    const int row0 = blockIdx.x * TILE_R;
    const int tx   = tid % COL4;
    const int ty   = tid / COL4;

    float4 acc[8];
#pragma unroll
    for (int j = 0; j < 8; ++j) acc[j] = make_float4(0.f, 0.f, 0.f, 0.f);

    for (int k0 = 0; k0 < 128; k0 += 32) {
        __syncthreads();
        // stage W chunk: rows k0..k0+31, flat float4 copy
        {
            constexpr int NF4 = 32 * NC / 4;
#pragma unroll
            for (int i = tid; i < NF4; i += 256)
                reinterpret_cast<float4*>(ws)[i] =
                    reinterpret_cast<const float4*>(W + (size_t)k0 * NC)[i];
        }
        // stage X tile chunk: TILE_R rows x 32 k
        {
            const int c = tid & 7;        // float4 within 32-k chunk
            const int rb = tid >> 3;      // 0..31
#pragma unroll
            for (int r = rb; r < TILE_R; r += 32) {
                const int gr = row0 + r;
                float4 v = make_float4(0.f, 0.f, 0.f, 0.f);
                if (gr < M)
                    v = *reinterpret_cast<const float4*>(X + (size_t)gr * 128 + k0 + c * 4);
                if (RELU) {
                    v.x = fmaxf(v.x, 0.f); v.y = fmaxf(v.y, 0.f);
                    v.z = fmaxf(v.z, 0.f); v.w = fmaxf(v.w, 0.f);
                }
                *reinterpret_cast<float4*>(&xs[r * XS_STRIDE + c * 4]) = v;
            }
        }
        __syncthreads();

#pragma unroll
        for (int kk = 0; kk < 32; kk += 4) {
            float4 wv[4];
#pragma unroll
            for (int i = 0; i < 4; ++i)
                wv[i] = *reinterpret_cast<const float4*>(&ws[(kk + i) * NC + tx * 4]);
#pragma unroll
            for (int j = 0; j < 8; ++j) {
                const float4 xv =
                    *reinterpret_cast<const float4*>(&xs[(ty + ROWT * j) * XS_STRIDE + kk]);
                acc[j].x = fmaf(xv.x, wv[0].x, acc[j].x);
                acc[j].y = fmaf(xv.x, wv[0].y, acc[j].y);
                acc[j].z = fmaf(xv.x, wv[0].z, acc[j].z);
                acc[j].w = fmaf(xv.x, wv[0].w, acc[j].w);
                acc[j].x = fmaf(xv.y, wv[1].x, acc[j].x);
                acc[j].y = fmaf(xv.y, wv[1].y, acc[j].y);
                acc[j].z = fmaf(xv.y, wv[1].z, acc[j].z);
                acc[j].w = fmaf(xv.y, wv[1].w, acc[j].w);
                acc[j].x = fmaf(xv.z, wv[2].x, acc[j].x);
                acc[j].y = fmaf(xv.z, wv[2].y, acc[j].y);
                acc[j].z = fmaf(xv.z, wv[2].z, acc[j].z);
                acc[j].w = fmaf(xv.z, wv[2].w, acc[j].w);
                acc[j].x = fmaf(xv.w, wv[3].x, acc[j].x);
                acc[j].y = fmaf(xv.w, wv[3].y, acc[j].y);
                acc[j].z = fmaf(xv.w, wv[3].z, acc[j].z);
                acc[j].w = fmaf(xv.w, wv[3].w, acc[j].w);
            }
        }
    }

#pragma unroll
    for (int j = 0; j < 8; ++j) {
        const int gr = row0 + ty + ROWT * j;
        if (gr < M) {
            ushort4 o;
            o.x = f2bf_rne(acc[j].x);
            o.y = f2bf_rne(acc[j].y);
            o.z = f2bf_rne(acc[j].z);
            o.w = f2bf_rne(acc[j].w);
            *reinterpret_cast<ushort4*>(Y + (size_t)gr * NC + tx * 4) = o;
        }
    }
}

// out[n](f32) = b + h[n]*dinv[n]^2 + sum_e h[src_e]*csr_w[e]*dinv[n]
// h is bf16 [N][C]; C/4 lanes per node, 4 channels (ushort4) per lane.
template <int C>
__global__ __launch_bounds__(256) void k_gather(const unsigned short* __restrict__ h,
                                                const int* __restrict__ row_ptr,
                                                const int* __restrict__ csr_src,
                                                const float* __restrict__ csr_w,
                                                const float* __restrict__ dinv,
                                                const float* __restrict__ b,
                                                float* __restrict__ out, int N) {
    constexpr int LPN = C / 4;  // 32 or 16
    const int tid  = blockIdx.x * blockDim.x + threadIdx.x;
    const int node = tid / LPN;
    const int lane = tid % LPN;
    if (node >= N) return;

    const float dn = dinv[node];
    float4 acc = reinterpret_cast<const float4*>(b)[lane];
    {
        const float w = dn * dn;  // self-loop
        const ushort4 v = *reinterpret_cast<const ushort4*>(h + (size_t)node * C + lane * 4);
        acc.x = fmaf(bf2f(v.x), w, acc.x); acc.y = fmaf(bf2f(v.y), w, acc.y);
        acc.z = fmaf(bf2f(v.z), w, acc.z); acc.w = fmaf(bf2f(v.w), w, acc.w);
    }

    const int e1 = row_ptr[node + 1];
    int e = row_ptr[node];
    for (; e + 1 < e1; e += 2) {
        const int s0 = csr_src[e];
        const int s1 = csr_src[e + 1];
        const float w0 = csr_w[e] * dn;
        const float w1 = csr_w[e + 1] * dn;
        const ushort4 v0 = *reinterpret_cast<const ushort4*>(h + (size_t)s0 * C + lane * 4);
        const ushort4 v1 = *reinterpret_cast<const ushort4*>(h + (size_t)s1 * C + lane * 4);
        acc.x = fmaf(bf2f(v0.x), w0, acc.x); acc.y = fmaf(bf2f(v0.y), w0, acc.y);
        acc.z = fmaf(bf2f(v0.z), w0, acc.z); acc.w = fmaf(bf2f(v0.w), w0, acc.w);
        acc.x = fmaf(bf2f(v1.x), w1, acc.x); acc.y = fmaf(bf2f(v1.y), w1, acc.y);
        acc.z = fmaf(bf2f(v1.z), w1, acc.z); acc.w = fmaf(bf2f(v1.w), w1, acc.w);
    }
    if (e < e1) {
        const int s0 = csr_src[e];
        const float w0 = csr_w[e] * dn;
        const ushort4 v0 = *reinterpret_cast<const ushort4*>(h + (size_t)s0 * C + lane * 4);
        acc.x = fmaf(bf2f(v0.x), w0, acc.x); acc.y = fmaf(bf2f(v0.y), w0, acc.y);
        acc.z = fmaf(bf2f(v0.z), w0, acc.z); acc.w = fmaf(bf2f(v0.w), w0, acc.w);
    }

    reinterpret_cast<float4*>(out + (size_t)node * C)[lane] = acc;
}

extern "C" void kernel_launch(void* const* d_in, const int* in_sizes, int n_in,
                              void* d_out, int out_size, void* d_ws, size_t ws_size,
                              hipStream_t stream) {
    const float* x  = (const float*)d_in[0];
    const int*   ei = (const int*)d_in[1];
    const float* W1 = (const float*)d_in[2];
    const float* b1 = (const float*)d_in[3];
    const float* W2 = (const float*)d_in[4];
    const float* b2 = (const float*)d_in[5];
    float* out = (float*)d_out;

    const int N = in_sizes[0] / IN_CH;   // 50000
    const int E = in_sizes[1] / 2;       // 600000

    char* wsb = (char*)d_ws;
    size_t off = 0;
    auto alloc = [&](size_t bytes) -> void* {
        void* p = wsb + off;
        off += (bytes + 255) & ~(size_t)255;
        return p;
    };
    int*   deg     = (int*)alloc((size_t)N * sizeof(int));
    int*   flag    = (int*)alloc(256);
    float* dinv    = (float*)alloc((size_t)N * sizeof(float));
    int*   row_ptr = (int*)alloc(((size_t)N + 1) * sizeof(int));
    int*   csr_src = (int*)alloc((size_t)E * sizeof(int));
    float* csr_w   = (float*)alloc((size_t)E * sizeof(float));
    unsigned short* h1b = (unsigned short*)alloc((size_t)N * HID * sizeof(unsigned short));
    float* agg1    = (float*)alloc((size_t)N * HID * sizeof(float));
    int*   cursor  = deg;                 // deg dead after k_dinv
    unsigned short* h2b = h1b;            // h1b dead after gather1 (6.4MB <= 12.8MB)

    auto gs = [](long long n) { return (int)((n + 255) / 256); };

    k_init<<<gs(N), 256, 0, stream>>>(deg, flag, N);
    k_detect64<<<2048, 256, 0, stream>>>(ei, flag, E);
    k_count<<<gs(E), 256, 0, stream>>>(ei, flag, deg, E);
    k_dinv<<<gs(N), 256, 0, stream>>>(deg, dinv, N);
    k_scan<<<1, 1024, 0, stream>>>(deg, row_ptr, cursor, N);
    k_fill<<<gs(E), 256, 0, stream>>>(ei, flag, dinv, cursor, csr_src, csr_w, E);

    // layer 1
    k_gemm<HID, false><<<(N + 63) / 64, 256, 0, stream>>>(x, W1, h1b, N);
    k_gather<HID><<<gs((long long)N * (HID / 4)), 256, 0, stream>>>(
        h1b, row_ptr, csr_src, csr_w, dinv, b1, agg1, N);

    // layer 2 (ReLU fused into GEMM2 staging)
    k_gemm<OUT_CH, true><<<(N + 127) / 128, 256, 0, stream>>>(agg1, W2, h2b, N);
    k_gather<OUT_CH><<<gs((long long)N * (OUT_CH / 4)), 256, 0, stream>>>(
        h2b, row_ptr, csr_src, csr_w, dinv, b2, out, N);
}

// Round 4
// 189.980 us; speedup vs baseline: 8.6546x; 1.1774x over previous
//
#include <hip/hip_runtime.h>

// GCN 2-layer encoder for MI355X (gfx950) — round 4.
// r3 post-mortem: single-block k_scan was top dispatch (48us, 0.16% occupancy,
// serial carry chain). Replaced with 3-kernel hierarchical scan (~2us each);
// k_init/k_dinv folded away (memsetAsync for deg/flag, dinv fused into scan1).
//
// Pipeline: memset(deg=0, flag=1byte) -> detect64 -> count(indeg)
//   -> scan1 (local excl scan + dinv) -> scan2 (partials) -> scan3 (apply+cursor)
//   -> fill(csr_src, csr_w) -> gemm<128> -> gather<128> -> gemm<64> -> gather<64>

constexpr int IN_CH  = 128;
constexpr int HID    = 128;
constexpr int OUT_CH = 64;
constexpr int SCAN_CHUNK = 4096;   // 256 threads x 16 elements

__device__ __forceinline__ unsigned short f2bf_rne(float f) {
    unsigned int u = __float_as_uint(f);
    u += 0x7FFFu + ((u >> 16) & 1u);
    return (unsigned short)(u >> 16);
}
__device__ __forceinline__ float bf2f(unsigned short h) {
    return __uint_as_float((unsigned int)h << 16);
}

__global__ void k_detect64(const int* __restrict__ ei, int* __restrict__ flag, int E) {
    int i = blockIdx.x * blockDim.x + threadIdx.x;
    for (int j = i; j < E; j += gridDim.x * blockDim.x) {
        if (ei[2 * j + 1] != 0) *flag = 0;   // race-free: all writers store 0
    }
}

__device__ __forceinline__ void load_edge(const int* __restrict__ ei, int e, int E,
                                          bool is64, int& s, int& d) {
    if (is64) { s = ei[2 * e]; d = ei[2 * (E + e)]; }
    else      { s = ei[e];     d = ei[E + e]; }
}

__global__ void k_count(const int* __restrict__ ei, const int* __restrict__ flag,
                        int* __restrict__ indeg, int E) {
    const bool is64 = (*flag != 0);
    int i = blockIdx.x * blockDim.x + threadIdx.x;
    for (int e = i; e < E; e += gridDim.x * blockDim.x) {
        int d = is64 ? ei[2 * (E + e)] : ei[E + e];
        atomicAdd(&indeg[d], 1);
    }
}

// Local exclusive scan of indeg over SCAN_CHUNK-sized blocks; also emits
// dinv[i] = rsqrt(indeg[i]+1) (the +1 is the self loop). partials[b] = total.
__global__ __launch_bounds__(256) void k_scan1(const int* __restrict__ indeg,
                                               int* __restrict__ row_ptr,
                                               float* __restrict__ dinv,
                                               int* __restrict__ partials, int N) {
    const int t    = threadIdx.x;
    const int base = blockIdx.x * SCAN_CHUNK + t * 16;
    int v[16];
    if (base + 15 < N) {
        const int4* p = reinterpret_cast<const int4*>(indeg + base);
#pragma unroll
        for (int q = 0; q < 4; ++q) {
            const int4 a = p[q];
            v[q * 4 + 0] = a.x; v[q * 4 + 1] = a.y;
            v[q * 4 + 2] = a.z; v[q * 4 + 3] = a.w;
        }
    } else {
#pragma unroll
        for (int j = 0; j < 16; ++j)
            v[j] = (base + j < N) ? indeg[base + j] : 0;
    }
#pragma unroll
    for (int j = 0; j < 16; ++j)
        if (base + j < N) dinv[base + j] = rsqrtf((float)(v[j] + 1));

    int sum = 0;
#pragma unroll
    for (int j = 0; j < 16; ++j) { const int tv = v[j]; v[j] = sum; sum += tv; }

    int incl = sum;
#pragma unroll
    for (int off = 1; off < 64; off <<= 1) {
        int tt = __shfl_up(incl, off, 64);
        if ((t & 63) >= off) incl += tt;
    }
    __shared__ int wsum[4];
    if ((t & 63) == 63) wsum[t >> 6] = incl;
    __syncthreads();
    int woff = 0;
#pragma unroll
    for (int w = 0; w < 4; ++w) woff += (w < (t >> 6)) ? wsum[w] : 0;
    const int texcl = woff + incl - sum;

#pragma unroll
    for (int j = 0; j < 16; ++j)
        if (base + j < N) row_ptr[base + j] = texcl + v[j];
    if (t == 255) partials[blockIdx.x] = woff + incl;
}

// Exclusive scan of partials (nblk <= 64, one wave); row_ptr[N] = grand total.
__global__ __launch_bounds__(64) void k_scan2(int* __restrict__ partials,
                                              int* __restrict__ row_ptr,
                                              int nblk, int N) {
    const int t = threadIdx.x;
    const int v = (t < nblk) ? partials[t] : 0;
    int incl = v;
#pragma unroll
    for (int off = 1; off < 64; off <<= 1) {
        int tt = __shfl_up(incl, off, 64);
        if (t >= off) incl += tt;
    }
    if (t < nblk) partials[t] = incl - v;
    if (t == nblk - 1) row_ptr[N] = incl;
}

// row_ptr[i] += partials[blk]; cursor[i] = row_ptr[i].
__global__ __launch_bounds__(256) void k_scan3(const int* __restrict__ partials,
                                               int* __restrict__ row_ptr,
                                               int* __restrict__ cursor, int N) {
    const int off  = partials[blockIdx.x];
    const int base = blockIdx.x * SCAN_CHUNK + threadIdx.x * 16;
    if (base + 15 < N) {
        int4* rp = reinterpret_cast<int4*>(row_ptr + base);
        int4* cp = reinterpret_cast<int4*>(cursor + base);
#pragma unroll
        for (int q = 0; q < 4; ++q) {
            int4 a = rp[q];
            a.x += off; a.y += off; a.z += off; a.w += off;
            rp[q] = a; cp[q] = a;
        }
    } else {
#pragma unroll
        for (int j = 0; j < 16; ++j) {
            const int i = base + j;
            if (i < N) { const int r = row_ptr[i] + off; row_ptr[i] = r; cursor[i] = r; }
        }
    }
}

__global__ void k_fill(const int* __restrict__ ei, const int* __restrict__ flag,
                       const float* __restrict__ dinv, int* __restrict__ cursor,
                       int* __restrict__ csr_src, float* __restrict__ csr_w, int E) {
    const bool is64 = (*flag != 0);
    int i = blockIdx.x * blockDim.x + threadIdx.x;
    for (int e = i; e < E; e += gridDim.x * blockDim.x) {
        int s, d;
        load_edge(ei, e, E, is64, s, d);
        const int pos = atomicAdd(&cursor[d], 1);
        csr_src[pos] = s;
        csr_w[pos]   = dinv[s];
    }
}

// Y[M x NC](bf16) = X[M x 128](f32, optional ReLU) @ W[128 x NC](f32).
// 8 rows x 4 cols per thread; all LDS reads ds_read_b128, conflict-free.
template <int NC, bool RELU>
__global__ __launch_bounds__(256) void k_gemm(const float* __restrict__ X,
                                              const float* __restrict__ W,
                                              unsigned short* __restrict__ Y, int M) {
    constexpr int COL4   = NC / 4;
    constexpr int ROWT   = 256 / COL4;
    constexpr int TILE_R = 8 * ROWT;
    constexpr int XS_STRIDE = 36;

    __shared__ __align__(16) float ws[32 * NC];
    __shared__ __align__(16) float xs[TILE_R * XS_STRIDE];

    const int tid  = threadIdx.x;
    const int row0 = blockIdx.x * TILE_R;
    const int tx   = tid % COL4;
    const int ty   = tid / COL4;

    float4 acc[8];
#pragma unroll
    for (int j = 0; j < 8; ++j) acc[j] = make_float4(0.f, 0.f, 0.f, 0.f);

    for (int k0 = 0; k0 < 128; k0 += 32) {
        __syncthreads();
        {
            constexpr int NF4 = 32 * NC / 4;
#pragma unroll
            for (int i = tid; i < NF4; i += 256)
                reinterpret_cast<float4*>(ws)[i] =
                    reinterpret_cast<const float4*>(W + (size_t)k0 * NC)[i];
        }
        {
            const int c  = tid & 7;
            const int rb = tid >> 3;
#pragma unroll
            for (int r = rb; r < TILE_R; r += 32) {
                const int gr = row0 + r;
                float4 v = make_float4(0.f, 0.f, 0.f, 0.f);
                if (gr < M)
                    v = *reinterpret_cast<const float4*>(X + (size_t)gr * 128 + k0 + c * 4);
                if (RELU) {
                    v.x = fmaxf(v.x, 0.f); v.y = fmaxf(v.y, 0.f);
                    v.z = fmaxf(v.z, 0.f); v.w = fmaxf(v.w, 0.f);
                }
                *reinterpret_cast<float4*>(&xs[r * XS_STRIDE + c * 4]) = v;
            }
        }
        __syncthreads();

#pragma unroll
        for (int kk = 0; kk < 32; kk += 4) {
            float4 wv[4];
#pragma unroll
            for (int i = 0; i < 4; ++i)
                wv[i] = *reinterpret_cast<const float4*>(&ws[(kk + i) * NC + tx * 4]);
#pragma unroll
            for (int j = 0; j < 8; ++j) {
                const float4 xv =
                    *reinterpret_cast<const float4*>(&xs[(ty + ROWT * j) * XS_STRIDE + kk]);
                acc[j].x = fmaf(xv.x, wv[0].x, acc[j].x);
                acc[j].y = fmaf(xv.x, wv[0].y, acc[j].y);
                acc[j].z = fmaf(xv.x, wv[0].z, acc[j].z);
                acc[j].w = fmaf(xv.x, wv[0].w, acc[j].w);
                acc[j].x = fmaf(xv.y, wv[1].x, acc[j].x);
                acc[j].y = fmaf(xv.y, wv[1].y, acc[j].y);
                acc[j].z = fmaf(xv.y, wv[1].z, acc[j].z);
                acc[j].w = fmaf(xv.y, wv[1].w, acc[j].w);
                acc[j].x = fmaf(xv.z, wv[2].x, acc[j].x);
                acc[j].y = fmaf(xv.z, wv[2].y, acc[j].y);
                acc[j].z = fmaf(xv.z, wv[2].z, acc[j].z);
                acc[j].w = fmaf(xv.z, wv[2].w, acc[j].w);
                acc[j].x = fmaf(xv.w, wv[3].x, acc[j].x);
                acc[j].y = fmaf(xv.w, wv[3].y, acc[j].y);
                acc[j].z = fmaf(xv.w, wv[3].z, acc[j].z);
                acc[j].w = fmaf(xv.w, wv[3].w, acc[j].w);
            }
        }
    }

#pragma unroll
    for (int j = 0; j < 8; ++j) {
        const int gr = row0 + ty + ROWT * j;
        if (gr < M) {
            ushort4 o;
            o.x = f2bf_rne(acc[j].x);
            o.y = f2bf_rne(acc[j].y);
            o.z = f2bf_rne(acc[j].z);
            o.w = f2bf_rne(acc[j].w);
            *reinterpret_cast<ushort4*>(Y + (size_t)gr * NC + tx * 4) = o;
        }
    }
}

// out[n](f32) = b + h[n]*dinv[n]^2 + sum_e h[src_e]*csr_w[e]*dinv[n]
template <int C>
__global__ __launch_bounds__(256) void k_gather(const unsigned short* __restrict__ h,
                                                const int* __restrict__ row_ptr,
                                                const int* __restrict__ csr_src,
                                                const float* __restrict__ csr_w,
                                                const float* __restrict__ dinv,
                                                const float* __restrict__ b,
                                                float* __restrict__ out, int N) {
    constexpr int LPN = C / 4;
    const int tid  = blockIdx.x * blockDim.x + threadIdx.x;
    const int node = tid / LPN;
    const int lane = tid % LPN;
    if (node >= N) return;

    const float dn = dinv[node];
    float4 acc = reinterpret_cast<const float4*>(b)[lane];
    {
        const float w = dn * dn;
        const ushort4 v = *reinterpret_cast<const ushort4*>(h + (size_t)node * C + lane * 4);
        acc.x = fmaf(bf2f(v.x), w, acc.x); acc.y = fmaf(bf2f(v.y), w, acc.y);
        acc.z = fmaf(bf2f(v.z), w, acc.z); acc.w = fmaf(bf2f(v.w), w, acc.w);
    }

    const int e1 = row_ptr[node + 1];
    int e = row_ptr[node];
    for (; e + 1 < e1; e += 2) {
        const int s0 = csr_src[e];
        const int s1 = csr_src[e + 1];
        const float w0 = csr_w[e] * dn;
        const float w1 = csr_w[e + 1] * dn;
        const ushort4 v0 = *reinterpret_cast<const ushort4*>(h + (size_t)s0 * C + lane * 4);
        const ushort4 v1 = *reinterpret_cast<const ushort4*>(h + (size_t)s1 * C + lane * 4);
        acc.x = fmaf(bf2f(v0.x), w0, acc.x); acc.y = fmaf(bf2f(v0.y), w0, acc.y);
        acc.z = fmaf(bf2f(v0.z), w0, acc.z); acc.w = fmaf(bf2f(v0.w), w0, acc.w);
        acc.x = fmaf(bf2f(v1.x), w1, acc.x); acc.y = fmaf(bf2f(v1.y), w1, acc.y);
        acc.z = fmaf(bf2f(v1.z), w1, acc.z); acc.w = fmaf(bf2f(v1.w), w1, acc.w);
    }
    if (e < e1) {
        const int s0 = csr_src[e];
        const float w0 = csr_w[e] * dn;
        const ushort4 v0 = *reinterpret_cast<const ushort4*>(h + (size_t)s0 * C + lane * 4);
        acc.x = fmaf(bf2f(v0.x), w0, acc.x); acc.y = fmaf(bf2f(v0.y), w0, acc.y);
        acc.z = fmaf(bf2f(v0.z), w0, acc.z); acc.w = fmaf(bf2f(v0.w), w0, acc.w);
    }

    reinterpret_cast<float4*>(out + (size_t)node * C)[lane] = acc;
}

extern "C" void kernel_launch(void* const* d_in, const int* in_sizes, int n_in,
                              void* d_out, int out_size, void* d_ws, size_t ws_size,
                              hipStream_t stream) {
    const float* x  = (const float*)d_in[0];
    const int*   ei = (const int*)d_in[1];
    const float* W1 = (const float*)d_in[2];
    const float* b1 = (const float*)d_in[3];
    const float* W2 = (const float*)d_in[4];
    const float* b2 = (const float*)d_in[5];
    float* out = (float*)d_out;

    const int N = in_sizes[0] / IN_CH;   // 50000
    const int E = in_sizes[1] / 2;       // 600000
    const int NBLK = (N + SCAN_CHUNK - 1) / SCAN_CHUNK;   // 13 (<= 64 supported)

    char* wsb = (char*)d_ws;
    size_t off = 0;
    auto alloc = [&](size_t bytes) -> void* {
        void* p = wsb + off;
        off += (bytes + 255) & ~(size_t)255;
        return p;
    };
    int*   indeg    = (int*)alloc((size_t)N * sizeof(int));
    int*   flag     = (int*)alloc(256);
    int*   partials = (int*)alloc(64 * sizeof(int));
    float* dinv     = (float*)alloc((size_t)N * sizeof(float));
    int*   row_ptr  = (int*)alloc(((size_t)N + 1) * sizeof(int));
    int*   csr_src  = (int*)alloc((size_t)E * sizeof(int));
    float* csr_w    = (float*)alloc((size_t)E * sizeof(float));
    unsigned short* h1b = (unsigned short*)alloc((size_t)N * HID * sizeof(unsigned short));
    float* agg1     = (float*)alloc((size_t)N * HID * sizeof(float));
    int*   cursor   = indeg;   // indeg dead after k_scan1
    unsigned short* h2b = h1b; // h1b dead after gather1

    auto gs = [](long long n) { return (int)((n + 255) / 256); };

    hipMemsetAsync(indeg, 0, (size_t)N * sizeof(int), stream);
    hipMemsetAsync(flag, 1, sizeof(int), stream);   // 0x01010101 != 0 -> "int64 unless disproven"

    k_detect64<<<1024, 256, 0, stream>>>(ei, flag, E);
    k_count<<<gs(E), 256, 0, stream>>>(ei, flag, indeg, E);
    k_scan1<<<NBLK, 256, 0, stream>>>(indeg, row_ptr, dinv, partials, N);
    k_scan2<<<1, 64, 0, stream>>>(partials, row_ptr, NBLK, N);
    k_scan3<<<NBLK, 256, 0, stream>>>(partials, row_ptr, cursor, N);
    k_fill<<<gs(E), 256, 0, stream>>>(ei, flag, dinv, cursor, csr_src, csr_w, E);

    // layer 1
    k_gemm<HID, false><<<(N + 63) / 64, 256, 0, stream>>>(x, W1, h1b, N);
    k_gather<HID><<<gs((long long)N * (HID / 4)), 256, 0, stream>>>(
        h1b, row_ptr, csr_src, csr_w, dinv, b1, agg1, N);

    // layer 2 (ReLU fused into GEMM2 staging)
    k_gemm<OUT_CH, true><<<(N + 127) / 128, 256, 0, stream>>>(agg1, W2, h2b, N);
    k_gather<OUT_CH><<<gs((long long)N * (OUT_CH / 4)), 256, 0, stream>>>(
        h2b, row_ptr, csr_src, csr_w, dinv, b2, out, N);
}

// Round 5
// 159.308 us; speedup vs baseline: 10.3209x; 1.1925x over previous
//
#include <hip/hip_runtime.h>

// GCN 2-layer encoder for MI355X (gfx950) — round 5.
// r4 post-mortem: hipMemsetAsync fills cost ~41us EACH (rocclr fill kernel),
// k_fill 42us (scattered 4B stores x2 arrays -> 66MB writeback across XCD L2s).
// r5: (a) own k_init instead of memsets; (b) per-wave int64 probe kills
// detect64+flag; (c) csr record = int2{src, w} -> one 8B store per edge;
// (d) k_fill fused into gemm1 dispatch (independent work, overlaps
// latency-bound fill with VALU-bound GEMM); (e) scan2 folded into scan3.
//
// Pipeline (8 dispatches):
//   k_init -> k_count -> k_scan1 -> k_scan3 -> k_gemm_fill(gemm1 || fill)
//   -> k_gather<128> -> k_gemm<64> -> k_gather<64>

constexpr int IN_CH  = 128;
constexpr int HID    = 128;
constexpr int OUT_CH = 64;
constexpr int SCAN_CHUNK = 4096;   // 256 threads x 16 elements

__device__ __forceinline__ unsigned short f2bf_rne(float f) {
    unsigned int u = __float_as_uint(f);
    u += 0x7FFFu + ((u >> 16) & 1u);
    return (unsigned short)(u >> 16);
}
__device__ __forceinline__ float bf2f(unsigned short h) {
    return __uint_as_float((unsigned int)h << 16);
}

// Wave-level dtype probe: odd dwords of the first 64 int64 lanes are hi-words
// (== 0 for node ids < 2^31). For int32 data they are random node ids;
// P(all 64 == 0) ~ 50000^-64. One coalesced 512B read per wave, L2-broadcast.
__device__ __forceinline__ bool probe_is64(const int* __restrict__ ei) {
    const int v = ei[2 * (threadIdx.x & 63) + 1];
    return __ballot(v != 0) == 0ull;
}

__global__ void k_init(int* __restrict__ indeg, int N) {
    const int i = blockIdx.x * blockDim.x + threadIdx.x;
    const int n4 = N / 4;
    for (int j = i; j < n4; j += gridDim.x * blockDim.x)
        reinterpret_cast<int4*>(indeg)[j] = make_int4(0, 0, 0, 0);
    const int tail = n4 * 4 + i;
    if (tail < N) indeg[tail] = 0;
}

__global__ void k_count(const int* __restrict__ ei, int* __restrict__ indeg, int E) {
    const bool is64 = probe_is64(ei);
    const int i = blockIdx.x * blockDim.x + threadIdx.x;
    for (int e = i; e < E; e += gridDim.x * blockDim.x) {
        const int d = is64 ? ei[2 * (E + e)] : ei[E + e];
        atomicAdd(&indeg[d], 1);
    }
}

// Local exclusive scan of indeg over SCAN_CHUNK blocks; emits dinv = rsqrt(indeg+1)
// (+1 = self loop) and partials[b] = block total.
__global__ __launch_bounds__(256) void k_scan1(const int* __restrict__ indeg,
                                               int* __restrict__ row_ptr,
                                               float* __restrict__ dinv,
                                               int* __restrict__ partials, int N) {
    const int t    = threadIdx.x;
    const int base = blockIdx.x * SCAN_CHUNK + t * 16;
    int v[16];
    if (base + 15 < N) {
        const int4* p = reinterpret_cast<const int4*>(indeg + base);
#pragma unroll
        for (int q = 0; q < 4; ++q) {
            const int4 a = p[q];
            v[q * 4 + 0] = a.x; v[q * 4 + 1] = a.y;
            v[q * 4 + 2] = a.z; v[q * 4 + 3] = a.w;
        }
    } else {
#pragma unroll
        for (int j = 0; j < 16; ++j)
            v[j] = (base + j < N) ? indeg[base + j] : 0;
    }
#pragma unroll
    for (int j = 0; j < 16; ++j)
        if (base + j < N) dinv[base + j] = rsqrtf((float)(v[j] + 1));

    int sum = 0;
#pragma unroll
    for (int j = 0; j < 16; ++j) { const int tv = v[j]; v[j] = sum; sum += tv; }

    int incl = sum;
#pragma unroll
    for (int off = 1; off < 64; off <<= 1) {
        int tt = __shfl_up(incl, off, 64);
        if ((t & 63) >= off) incl += tt;
    }
    __shared__ int wsum[4];
    if ((t & 63) == 63) wsum[t >> 6] = incl;
    __syncthreads();
    int woff = 0;
#pragma unroll
    for (int w = 0; w < 4; ++w) woff += (w < (t >> 6)) ? wsum[w] : 0;
    const int texcl = woff + incl - sum;

#pragma unroll
    for (int j = 0; j < 16; ++j)
        if (base + j < N) row_ptr[base + j] = texcl + v[j];
    if (t == 255) partials[blockIdx.x] = woff + incl;
}

// Apply block offsets (each block prefix-sums the <=16 partials itself),
// write cursor; last block writes row_ptr[N] = grand total.
__global__ __launch_bounds__(256) void k_scan3(const int* __restrict__ partials,
                                               int* __restrict__ row_ptr,
                                               int* __restrict__ cursor,
                                               int N, int nblk) {
    int off = 0;
    for (int w = 0; w < (int)blockIdx.x; ++w) off += partials[w];

    const int base = blockIdx.x * SCAN_CHUNK + threadIdx.x * 16;
    if (base + 15 < N) {
        int4* rp = reinterpret_cast<int4*>(row_ptr + base);
        int4* cp = reinterpret_cast<int4*>(cursor + base);
#pragma unroll
        for (int q = 0; q < 4; ++q) {
            int4 a = rp[q];
            a.x += off; a.y += off; a.z += off; a.w += off;
            rp[q] = a; cp[q] = a;
        }
    } else {
#pragma unroll
        for (int j = 0; j < 16; ++j) {
            const int i = base + j;
            if (i < N) { const int r = row_ptr[i] + off; row_ptr[i] = r; cursor[i] = r; }
        }
    }
    if ((int)blockIdx.x == nblk - 1 && threadIdx.x == 255)
        row_ptr[N] = off + partials[nblk - 1];
}

// GEMM body: Y[M x NC](bf16) = X[M x 128](f32, opt ReLU) @ W[128 x NC](f32).
// 8 rows x 4 cols per thread; all LDS reads ds_read_b128, conflict-free.
template <int NC, bool RELU>
__device__ __forceinline__ void gemm_body(const float* __restrict__ X,
                                          const float* __restrict__ W,
                                          unsigned short* __restrict__ Y,
                                          int M, int blk) {
    constexpr int COL4   = NC / 4;
    constexpr int ROWT   = 256 / COL4;
    constexpr int TILE_R = 8 * ROWT;
    constexpr int XS_STRIDE = 36;

    __shared__ __align__(16) float ws[32 * NC];
    __shared__ __align__(16) float xs[TILE_R * XS_STRIDE];

    const int tid  = threadIdx.x;
    const int row0 = blk * TILE_R;
    const int tx   = tid % COL4;
    const int ty   = tid / COL4;

    float4 acc[8];
#pragma unroll
    for (int j = 0; j < 8; ++j) acc[j] = make_float4(0.f, 0.f, 0.f, 0.f);

    for (int k0 = 0; k0 < 128; k0 += 32) {
        __syncthreads();
        {
            constexpr int NF4 = 32 * NC / 4;
#pragma unroll
            for (int i = tid; i < NF4; i += 256)
                reinterpret_cast<float4*>(ws)[i] =
                    reinterpret_cast<const float4*>(W + (size_t)k0 * NC)[i];
        }
        {
            const int c  = tid & 7;
            const int rb = tid >> 3;
#pragma unroll
            for (int r = rb; r < TILE_R; r += 32) {
                const int gr = row0 + r;
                float4 v = make_float4(0.f, 0.f, 0.f, 0.f);
                if (gr < M)
                    v = *reinterpret_cast<const float4*>(X + (size_t)gr * 128 + k0 + c * 4);
                if (RELU) {
                    v.x = fmaxf(v.x, 0.f); v.y = fmaxf(v.y, 0.f);
                    v.z = fmaxf(v.z, 0.f); v.w = fmaxf(v.w, 0.f);
                }
                *reinterpret_cast<float4*>(&xs[r * XS_STRIDE + c * 4]) = v;
            }
        }
        __syncthreads();

#pragma unroll
        for (int kk = 0; kk < 32; kk += 4) {
            float4 wv[4];
#pragma unroll
            for (int i = 0; i < 4; ++i)
                wv[i] = *reinterpret_cast<const float4*>(&ws[(kk + i) * NC + tx * 4]);
#pragma unroll
            for (int j = 0; j < 8; ++j) {
                const float4 xv =
                    *reinterpret_cast<const float4*>(&xs[(ty + ROWT * j) * XS_STRIDE + kk]);
                acc[j].x = fmaf(xv.x, wv[0].x, acc[j].x);
                acc[j].y = fmaf(xv.x, wv[0].y, acc[j].y);
                acc[j].z = fmaf(xv.x, wv[0].z, acc[j].z);
                acc[j].w = fmaf(xv.x, wv[0].w, acc[j].w);
                acc[j].x = fmaf(xv.y, wv[1].x, acc[j].x);
                acc[j].y = fmaf(xv.y, wv[1].y, acc[j].y);
                acc[j].z = fmaf(xv.y, wv[1].z, acc[j].z);
                acc[j].w = fmaf(xv.y, wv[1].w, acc[j].w);
                acc[j].x = fmaf(xv.z, wv[2].x, acc[j].x);
                acc[j].y = fmaf(xv.z, wv[2].y, acc[j].y);
                acc[j].z = fmaf(xv.z, wv[2].z, acc[j].z);
                acc[j].w = fmaf(xv.z, wv[2].w, acc[j].w);
                acc[j].x = fmaf(xv.w, wv[3].x, acc[j].x);
                acc[j].y = fmaf(xv.w, wv[3].y, acc[j].y);
                acc[j].z = fmaf(xv.w, wv[3].z, acc[j].z);
                acc[j].w = fmaf(xv.w, wv[3].w, acc[j].w);
            }
        }
    }

#pragma unroll
    for (int j = 0; j < 8; ++j) {
        const int gr = row0 + ty + ROWT * j;
        if (gr < M) {
            ushort4 o;
            o.x = f2bf_rne(acc[j].x);
            o.y = f2bf_rne(acc[j].y);
            o.z = f2bf_rne(acc[j].z);
            o.w = f2bf_rne(acc[j].w);
            *reinterpret_cast<ushort4*>(Y + (size_t)gr * NC + tx * 4) = o;
        }
    }
}

// Dual-role dispatch: blocks [0, gemmBlocks) run gemm1; the rest run the CSR
// fill (independent work; overlaps latency-bound fill under VALU-bound GEMM).
__global__ __launch_bounds__(256) void k_gemm_fill(
    const float* __restrict__ X, const float* __restrict__ W,
    unsigned short* __restrict__ Y, int M, int gemmBlocks,
    const int* __restrict__ ei, const float* __restrict__ dinv,
    int* __restrict__ cursor, int2* __restrict__ csr, int E) {
    if ((int)blockIdx.x < gemmBlocks) {
        gemm_body<HID, false>(X, W, Y, M, blockIdx.x);
    } else {
        const bool is64 = probe_is64(ei);
        const int nthr  = (gridDim.x - gemmBlocks) * 256;
        const int start = (blockIdx.x - gemmBlocks) * 256 + threadIdx.x;
        for (int e = start; e < E; e += nthr) {
            int s, d;
            if (is64) { s = ei[2 * e]; d = ei[2 * (E + e)]; }
            else      { s = ei[e];     d = ei[E + e]; }
            const int pos = atomicAdd(&cursor[d], 1);
            csr[pos] = make_int2(s, __float_as_int(dinv[s]));
        }
    }
}

template <int NC, bool RELU>
__global__ __launch_bounds__(256) void k_gemm(const float* __restrict__ X,
                                              const float* __restrict__ W,
                                              unsigned short* __restrict__ Y, int M) {
    gemm_body<NC, RELU>(X, W, Y, M, blockIdx.x);
}

// out[n](f32) = b + h[n]*dinv[n]^2 + sum_e h[rec.src]*rec.w*dinv[n]
template <int C>
__global__ __launch_bounds__(256) void k_gather(const unsigned short* __restrict__ h,
                                                const int* __restrict__ row_ptr,
                                                const int2* __restrict__ csr,
                                                const float* __restrict__ dinv,
                                                const float* __restrict__ b,
                                                float* __restrict__ out, int N) {
    constexpr int LPN = C / 4;
    const int tid  = blockIdx.x * blockDim.x + threadIdx.x;
    const int node = tid / LPN;
    const int lane = tid % LPN;
    if (node >= N) return;

    const float dn = dinv[node];
    float4 acc = reinterpret_cast<const float4*>(b)[lane];
    {
        const float w = dn * dn;  // self loop
        const ushort4 v = *reinterpret_cast<const ushort4*>(h + (size_t)node * C + lane * 4);
        acc.x = fmaf(bf2f(v.x), w, acc.x); acc.y = fmaf(bf2f(v.y), w, acc.y);
        acc.z = fmaf(bf2f(v.z), w, acc.z); acc.w = fmaf(bf2f(v.w), w, acc.w);
    }

    const int e1 = row_ptr[node + 1];
    int e = row_ptr[node];
    for (; e + 1 < e1; e += 2) {
        const int2 r0 = csr[e];
        const int2 r1 = csr[e + 1];
        const float w0 = __int_as_float(r0.y) * dn;
        const float w1 = __int_as_float(r1.y) * dn;
        const ushort4 v0 = *reinterpret_cast<const ushort4*>(h + (size_t)r0.x * C + lane * 4);
        const ushort4 v1 = *reinterpret_cast<const ushort4*>(h + (size_t)r1.x * C + lane * 4);
        acc.x = fmaf(bf2f(v0.x), w0, acc.x); acc.y = fmaf(bf2f(v0.y), w0, acc.y);
        acc.z = fmaf(bf2f(v0.z), w0, acc.z); acc.w = fmaf(bf2f(v0.w), w0, acc.w);
        acc.x = fmaf(bf2f(v1.x), w1, acc.x); acc.y = fmaf(bf2f(v1.y), w1, acc.y);
        acc.z = fmaf(bf2f(v1.z), w1, acc.z); acc.w = fmaf(bf2f(v1.w), w1, acc.w);
    }
    if (e < e1) {
        const int2 r0 = csr[e];
        const float w0 = __int_as_float(r0.y) * dn;
        const ushort4 v0 = *reinterpret_cast<const ushort4*>(h + (size_t)r0.x * C + lane * 4);
        acc.x = fmaf(bf2f(v0.x), w0, acc.x); acc.y = fmaf(bf2f(v0.y), w0, acc.y);
        acc.z = fmaf(bf2f(v0.z), w0, acc.z); acc.w = fmaf(bf2f(v0.w), w0, acc.w);
    }

    reinterpret_cast<float4*>(out + (size_t)node * C)[lane] = acc;
}

extern "C" void kernel_launch(void* const* d_in, const int* in_sizes, int n_in,
                              void* d_out, int out_size, void* d_ws, size_t ws_size,
                              hipStream_t stream) {
    const float* x  = (const float*)d_in[0];
    const int*   ei = (const int*)d_in[1];
    const float* W1 = (const float*)d_in[2];
    const float* b1 = (const float*)d_in[3];
    const float* W2 = (const float*)d_in[4];
    const float* b2 = (const float*)d_in[5];
    float* out = (float*)d_out;

    const int N = in_sizes[0] / IN_CH;   // 50000
    const int E = in_sizes[1] / 2;       // 600000
    const int NBLK = (N + SCAN_CHUNK - 1) / SCAN_CHUNK;   // 13

    char* wsb = (char*)d_ws;
    size_t off = 0;
    auto alloc = [&](size_t bytes) -> void* {
        void* p = wsb + off;
        off += (bytes + 255) & ~(size_t)255;
        return p;
    };
    int*   indeg    = (int*)alloc((size_t)N * sizeof(int));
    int*   partials = (int*)alloc(64 * sizeof(int));
    float* dinv     = (float*)alloc((size_t)N * sizeof(float));
    int*   row_ptr  = (int*)alloc(((size_t)N + 1) * sizeof(int));
    int2*  csr      = (int2*)alloc((size_t)E * sizeof(int2));
    unsigned short* h1b = (unsigned short*)alloc((size_t)N * HID * sizeof(unsigned short));
    float* agg1     = (float*)alloc((size_t)N * HID * sizeof(float));
    int*   cursor   = indeg;   // indeg dead after k_scan1
    unsigned short* h2b = h1b; // h1b dead after gather1

    auto gs = [](long long n) { return (int)((n + 255) / 256); };

    k_init<<<64, 256, 0, stream>>>(indeg, N);
    k_count<<<gs(E), 256, 0, stream>>>(ei, indeg, E);
    k_scan1<<<NBLK, 256, 0, stream>>>(indeg, row_ptr, dinv, partials, N);
    k_scan3<<<NBLK, 256, 0, stream>>>(partials, row_ptr, cursor, N, NBLK);

    // layer 1 transform fused with CSR fill (independent work)
    const int gemmBlocks = (N + 63) / 64;        // 782
    const int fillBlocks = 512;
    k_gemm_fill<<<gemmBlocks + fillBlocks, 256, 0, stream>>>(
        x, W1, h1b, N, gemmBlocks, ei, dinv, cursor, csr, E);

    k_gather<HID><<<gs((long long)N * (HID / 4)), 256, 0, stream>>>(
        h1b, row_ptr, csr, dinv, b1, agg1, N);

    // layer 2 (ReLU fused into GEMM2 staging)
    k_gemm<OUT_CH, true><<<(N + 127) / 128, 256, 0, stream>>>(agg1, W2, h2b, N);
    k_gather<OUT_CH><<<gs((long long)N * (OUT_CH / 4)), 256, 0, stream>>>(
        h2b, row_ptr, csr, dinv, b2, out, N);
}

// Round 6
// 158.007 us; speedup vs baseline: 10.4059x; 1.0082x over previous
//
#include <hip/hip_runtime.h>

// GCN 2-layer encoder for MI355X (gfx950) — round 6.
// r5 post-mortem: gemm_fill 47us == fill-alone (gemm1 fully hidden; fill is
// scattered-8B-store writeback-bound, 52MB for 4.8MB payload). gather<128> 25
// + gemm<64> 12 + agg1 51MB round-trip were the next block.
// r6: (a) gather1+ReLU+gemm2 fused per 64-row tile (agg1 never materialized,
// gather memory overlaps GEMM VALU across blocks); (b) fill store is a single
// nontemporal 8B record.
//
// Pipeline (7 dispatches):
//   k_init -> k_count -> k_scan1 -> k_scan3 -> k_gemm_fill(gemm1 || fill)
//   -> k_gather_gemm2(h1b -> h2b) -> k_gather<64>(h2b -> out)

constexpr int IN_CH  = 128;
constexpr int HID    = 128;
constexpr int OUT_CH = 64;
constexpr int SCAN_CHUNK = 4096;   // 256 threads x 16 elements

__device__ __forceinline__ unsigned short f2bf_rne(float f) {
    unsigned int u = __float_as_uint(f);
    u += 0x7FFFu + ((u >> 16) & 1u);
    return (unsigned short)(u >> 16);
}
__device__ __forceinline__ float bf2f(unsigned short h) {
    return __uint_as_float((unsigned int)h << 16);
}

// Wave-level dtype probe: odd dwords of the first 64 int64 lanes are hi-words
// (== 0 for node ids < 2^31). For int32 data they are random node ids.
__device__ __forceinline__ bool probe_is64(const int* __restrict__ ei) {
    const int v = ei[2 * (threadIdx.x & 63) + 1];
    return __ballot(v != 0) == 0ull;
}

__global__ void k_init(int* __restrict__ indeg, int N) {
    const int i = blockIdx.x * blockDim.x + threadIdx.x;
    const int n4 = N / 4;
    for (int j = i; j < n4; j += gridDim.x * blockDim.x)
        reinterpret_cast<int4*>(indeg)[j] = make_int4(0, 0, 0, 0);
    const int tail = n4 * 4 + i;
    if (tail < N) indeg[tail] = 0;
}

__global__ void k_count(const int* __restrict__ ei, int* __restrict__ indeg, int E) {
    const bool is64 = probe_is64(ei);
    const int i = blockIdx.x * blockDim.x + threadIdx.x;
    for (int e = i; e < E; e += gridDim.x * blockDim.x) {
        const int d = is64 ? ei[2 * (E + e)] : ei[E + e];
        atomicAdd(&indeg[d], 1);
    }
}

// Local exclusive scan of indeg over SCAN_CHUNK blocks; emits dinv = rsqrt(indeg+1)
// (+1 = self loop) and partials[b] = block total.
__global__ __launch_bounds__(256) void k_scan1(const int* __restrict__ indeg,
                                               int* __restrict__ row_ptr,
                                               float* __restrict__ dinv,
                                               int* __restrict__ partials, int N) {
    const int t    = threadIdx.x;
    const int base = blockIdx.x * SCAN_CHUNK + t * 16;
    int v[16];
    if (base + 15 < N) {
        const int4* p = reinterpret_cast<const int4*>(indeg + base);
#pragma unroll
        for (int q = 0; q < 4; ++q) {
            const int4 a = p[q];
            v[q * 4 + 0] = a.x; v[q * 4 + 1] = a.y;
            v[q * 4 + 2] = a.z; v[q * 4 + 3] = a.w;
        }
    } else {
#pragma unroll
        for (int j = 0; j < 16; ++j)
            v[j] = (base + j < N) ? indeg[base + j] : 0;
    }
#pragma unroll
    for (int j = 0; j < 16; ++j)
        if (base + j < N) dinv[base + j] = rsqrtf((float)(v[j] + 1));

    int sum = 0;
#pragma unroll
    for (int j = 0; j < 16; ++j) { const int tv = v[j]; v[j] = sum; sum += tv; }

    int incl = sum;
#pragma unroll
    for (int off = 1; off < 64; off <<= 1) {
        int tt = __shfl_up(incl, off, 64);
        if ((t & 63) >= off) incl += tt;
    }
    __shared__ int wsum[4];
    if ((t & 63) == 63) wsum[t >> 6] = incl;
    __syncthreads();
    int woff = 0;
#pragma unroll
    for (int w = 0; w < 4; ++w) woff += (w < (t >> 6)) ? wsum[w] : 0;
    const int texcl = woff + incl - sum;

#pragma unroll
    for (int j = 0; j < 16; ++j)
        if (base + j < N) row_ptr[base + j] = texcl + v[j];
    if (t == 255) partials[blockIdx.x] = woff + incl;
}

// Apply block offsets; write cursor; last block writes row_ptr[N].
__global__ __launch_bounds__(256) void k_scan3(const int* __restrict__ partials,
                                               int* __restrict__ row_ptr,
                                               int* __restrict__ cursor,
                                               int N, int nblk) {
    int off = 0;
    for (int w = 0; w < (int)blockIdx.x; ++w) off += partials[w];

    const int base = blockIdx.x * SCAN_CHUNK + threadIdx.x * 16;
    if (base + 15 < N) {
        int4* rp = reinterpret_cast<int4*>(row_ptr + base);
        int4* cp = reinterpret_cast<int4*>(cursor + base);
#pragma unroll
        for (int q = 0; q < 4; ++q) {
            int4 a = rp[q];
            a.x += off; a.y += off; a.z += off; a.w += off;
            rp[q] = a; cp[q] = a;
        }
    } else {
#pragma unroll
        for (int j = 0; j < 16; ++j) {
            const int i = base + j;
            if (i < N) { const int r = row_ptr[i] + off; row_ptr[i] = r; cursor[i] = r; }
        }
    }
    if ((int)blockIdx.x == nblk - 1 && threadIdx.x == 255)
        row_ptr[N] = off + partials[nblk - 1];
}

// GEMM body: Y[M x NC](bf16) = X[M x 128](f32, opt ReLU) @ W[128 x NC](f32).
template <int NC, bool RELU>
__device__ __forceinline__ void gemm_body(const float* __restrict__ X,
                                          const float* __restrict__ W,
                                          unsigned short* __restrict__ Y,
                                          int M, int blk) {
    constexpr int COL4   = NC / 4;
    constexpr int ROWT   = 256 / COL4;
    constexpr int TILE_R = 8 * ROWT;
    constexpr int XS_STRIDE = 36;

    __shared__ __align__(16) float ws[32 * NC];
    __shared__ __align__(16) float xs[TILE_R * XS_STRIDE];

    const int tid  = threadIdx.x;
    const int row0 = blk * TILE_R;
    const int tx   = tid % COL4;
    const int ty   = tid / COL4;

    float4 acc[8];
#pragma unroll
    for (int j = 0; j < 8; ++j) acc[j] = make_float4(0.f, 0.f, 0.f, 0.f);

    for (int k0 = 0; k0 < 128; k0 += 32) {
        __syncthreads();
        {
            constexpr int NF4 = 32 * NC / 4;
#pragma unroll
            for (int i = tid; i < NF4; i += 256)
                reinterpret_cast<float4*>(ws)[i] =
                    reinterpret_cast<const float4*>(W + (size_t)k0 * NC)[i];
        }
        {
            const int c  = tid & 7;
            const int rb = tid >> 3;
#pragma unroll
            for (int r = rb; r < TILE_R; r += 32) {
                const int gr = row0 + r;
                float4 v = make_float4(0.f, 0.f, 0.f, 0.f);
                if (gr < M)
                    v = *reinterpret_cast<const float4*>(X + (size_t)gr * 128 + k0 + c * 4);
                if (RELU) {
                    v.x = fmaxf(v.x, 0.f); v.y = fmaxf(v.y, 0.f);
                    v.z = fmaxf(v.z, 0.f); v.w = fmaxf(v.w, 0.f);
                }
                *reinterpret_cast<float4*>(&xs[r * XS_STRIDE + c * 4]) = v;
            }
        }
        __syncthreads();

#pragma unroll
        for (int kk = 0; kk < 32; kk += 4) {
            float4 wv[4];
#pragma unroll
            for (int i = 0; i < 4; ++i)
                wv[i] = *reinterpret_cast<const float4*>(&ws[(kk + i) * NC + tx * 4]);
#pragma unroll
            for (int j = 0; j < 8; ++j) {
                const float4 xv =
                    *reinterpret_cast<const float4*>(&xs[(ty + ROWT * j) * XS_STRIDE + kk]);
                acc[j].x = fmaf(xv.x, wv[0].x, acc[j].x);
                acc[j].y = fmaf(xv.x, wv[0].y, acc[j].y);
                acc[j].z = fmaf(xv.x, wv[0].z, acc[j].z);
                acc[j].w = fmaf(xv.x, wv[0].w, acc[j].w);
                acc[j].x = fmaf(xv.y, wv[1].x, acc[j].x);
                acc[j].y = fmaf(xv.y, wv[1].y, acc[j].y);
                acc[j].z = fmaf(xv.y, wv[1].z, acc[j].z);
                acc[j].w = fmaf(xv.y, wv[1].w, acc[j].w);
                acc[j].x = fmaf(xv.z, wv[2].x, acc[j].x);
                acc[j].y = fmaf(xv.z, wv[2].y, acc[j].y);
                acc[j].z = fmaf(xv.z, wv[2].z, acc[j].z);
                acc[j].w = fmaf(xv.z, wv[2].w, acc[j].w);
                acc[j].x = fmaf(xv.w, wv[3].x, acc[j].x);
                acc[j].y = fmaf(xv.w, wv[3].y, acc[j].y);
                acc[j].z = fmaf(xv.w, wv[3].z, acc[j].z);
                acc[j].w = fmaf(xv.w, wv[3].w, acc[j].w);
            }
        }
    }

#pragma unroll
    for (int j = 0; j < 8; ++j) {
        const int gr = row0 + ty + ROWT * j;
        if (gr < M) {
            ushort4 o;
            o.x = f2bf_rne(acc[j].x);
            o.y = f2bf_rne(acc[j].y);
            o.z = f2bf_rne(acc[j].z);
            o.w = f2bf_rne(acc[j].w);
            *reinterpret_cast<ushort4*>(Y + (size_t)gr * NC + tx * 4) = o;
        }
    }
}

// Dual-role dispatch: blocks [0, gemmBlocks) run gemm1; the rest run the CSR
// fill (nontemporal 8B record per edge).
__global__ __launch_bounds__(256) void k_gemm_fill(
    const float* __restrict__ X, const float* __restrict__ W,
    unsigned short* __restrict__ Y, int M, int gemmBlocks,
    const int* __restrict__ ei, const float* __restrict__ dinv,
    int* __restrict__ cursor, int2* __restrict__ csr, int E) {
    if ((int)blockIdx.x < gemmBlocks) {
        gemm_body<HID, false>(X, W, Y, M, blockIdx.x);
    } else {
        const bool is64 = probe_is64(ei);
        const int nthr  = (gridDim.x - gemmBlocks) * 256;
        const int start = (blockIdx.x - gemmBlocks) * 256 + threadIdx.x;
        for (int e = start; e < E; e += nthr) {
            int s, d;
            if (is64) { s = ei[2 * e]; d = ei[2 * (E + e)]; }
            else      { s = ei[e];     d = ei[E + e]; }
            const int pos = atomicAdd(&cursor[d], 1);
            const unsigned long long rec =
                (unsigned long long)(unsigned int)s |
                ((unsigned long long)__float_as_uint(dinv[s]) << 32);
            __builtin_nontemporal_store(
                rec, reinterpret_cast<unsigned long long*>(csr) + pos);
        }
    }
}

// Fused gather1 + ReLU + GEMM2: per block, 64 nodes.
// Phase 1: 4 lanes/node x 32 channels gather-reduce (bf16 h1b, f32 acc),
//          + self loop + b1, ReLU, write f32 row to LDS xs[64][132].
// Phase 2: xs @ W2 (W2 staged in two 64-row LDS chunks), emit bf16 h2b.
__global__ __launch_bounds__(256) void k_gather_gemm2(
    const unsigned short* __restrict__ h1b, const int* __restrict__ row_ptr,
    const int2* __restrict__ csr, const float* __restrict__ dinv,
    const float* __restrict__ b1, const float* __restrict__ W2,
    unsigned short* __restrict__ h2b, int N) {
    constexpr int TILE_R = 64;
    constexpr int XSS    = 132;
    __shared__ __align__(16) float xs[TILE_R * XSS];   // 33.8 KB
    __shared__ __align__(16) float ws[64 * OUT_CH];    // 16 KB

    const int tid  = threadIdx.x;
    const int row0 = blockIdx.x * TILE_R;

    // ---- phase 1: gather ----
    {
        const int r    = tid >> 2;       // local node 0..63
        const int lane = tid & 3;        // 32-channel block
        const int node = row0 + r;
        const int c0   = lane * 32;
        const bool valid = node < N;

        float4 acc[8];
        if (valid) {
#pragma unroll
            for (int q = 0; q < 8; ++q)
                acc[q] = reinterpret_cast<const float4*>(b1 + c0)[q];
            const float dn = dinv[node];
            const float wself = dn * dn;
            const unsigned short* hp = h1b + (size_t)node * HID + c0;
#pragma unroll
            for (int q = 0; q < 8; ++q) {
                const ushort4 v = reinterpret_cast<const ushort4*>(hp)[q];
                acc[q].x = fmaf(bf2f(v.x), wself, acc[q].x);
                acc[q].y = fmaf(bf2f(v.y), wself, acc[q].y);
                acc[q].z = fmaf(bf2f(v.z), wself, acc[q].z);
                acc[q].w = fmaf(bf2f(v.w), wself, acc[q].w);
            }
            const int e1 = row_ptr[node + 1];
            for (int e = row_ptr[node]; e < e1; ++e) {
                const int2 rec = csr[e];
                const float w = __int_as_float(rec.y) * dn;
                const unsigned short* sp = h1b + (size_t)rec.x * HID + c0;
#pragma unroll
                for (int q = 0; q < 8; ++q) {
                    const ushort4 v = reinterpret_cast<const ushort4*>(sp)[q];
                    acc[q].x = fmaf(bf2f(v.x), w, acc[q].x);
                    acc[q].y = fmaf(bf2f(v.y), w, acc[q].y);
                    acc[q].z = fmaf(bf2f(v.z), w, acc[q].z);
                    acc[q].w = fmaf(bf2f(v.w), w, acc[q].w);
                }
            }
        } else {
#pragma unroll
            for (int q = 0; q < 8; ++q) acc[q] = make_float4(0.f, 0.f, 0.f, 0.f);
        }
        // ReLU + write row slice to LDS
#pragma unroll
        for (int q = 0; q < 8; ++q) {
            float4 a = acc[q];
            a.x = fmaxf(a.x, 0.f); a.y = fmaxf(a.y, 0.f);
            a.z = fmaxf(a.z, 0.f); a.w = fmaxf(a.w, 0.f);
            *reinterpret_cast<float4*>(&xs[r * XSS + c0 + 4 * q]) = a;
        }
    }

    // ---- phase 2: GEMM xs(64x128) @ W2(128x64) ----
    const int tx = tid & 15;    // col group (4 cols)
    const int ty = tid >> 4;    // rows ty + 16j
    float4 acc2[4];
#pragma unroll
    for (int j = 0; j < 4; ++j) acc2[j] = make_float4(0.f, 0.f, 0.f, 0.f);

    for (int k0 = 0; k0 < 128; k0 += 64) {
        __syncthreads();   // xs ready (iter 0) / previous ws consumed (iter 1)
        for (int i = tid; i < 64 * OUT_CH / 4; i += 256)
            reinterpret_cast<float4*>(ws)[i] =
                reinterpret_cast<const float4*>(W2 + (size_t)k0 * OUT_CH)[i];
        __syncthreads();
#pragma unroll
        for (int kk = 0; kk < 64; kk += 4) {
            float4 wv[4];
#pragma unroll
            for (int i = 0; i < 4; ++i)
                wv[i] = *reinterpret_cast<const float4*>(&ws[(kk + i) * OUT_CH + tx * 4]);
#pragma unroll
            for (int j = 0; j < 4; ++j) {
                const float4 xv =
                    *reinterpret_cast<const float4*>(&xs[(ty + 16 * j) * XSS + k0 + kk]);
                acc2[j].x = fmaf(xv.x, wv[0].x, acc2[j].x);
                acc2[j].y = fmaf(xv.x, wv[0].y, acc2[j].y);
                acc2[j].z = fmaf(xv.x, wv[0].z, acc2[j].z);
                acc2[j].w = fmaf(xv.x, wv[0].w, acc2[j].w);
                acc2[j].x = fmaf(xv.y, wv[1].x, acc2[j].x);
                acc2[j].y = fmaf(xv.y, wv[1].y, acc2[j].y);
                acc2[j].z = fmaf(xv.y, wv[1].z, acc2[j].z);
                acc2[j].w = fmaf(xv.y, wv[1].w, acc2[j].w);
                acc2[j].x = fmaf(xv.z, wv[2].x, acc2[j].x);
                acc2[j].y = fmaf(xv.z, wv[2].y, acc2[j].y);
                acc2[j].z = fmaf(xv.z, wv[2].z, acc2[j].z);
                acc2[j].w = fmaf(xv.z, wv[2].w, acc2[j].w);
                acc2[j].x = fmaf(xv.w, wv[3].x, acc2[j].x);
                acc2[j].y = fmaf(xv.w, wv[3].y, acc2[j].y);
                acc2[j].z = fmaf(xv.w, wv[3].z, acc2[j].z);
                acc2[j].w = fmaf(xv.w, wv[3].w, acc2[j].w);
            }
        }
    }

#pragma unroll
    for (int j = 0; j < 4; ++j) {
        const int gr = row0 + ty + 16 * j;
        if (gr < N) {
            ushort4 o;
            o.x = f2bf_rne(acc2[j].x);
            o.y = f2bf_rne(acc2[j].y);
            o.z = f2bf_rne(acc2[j].z);
            o.w = f2bf_rne(acc2[j].w);
            *reinterpret_cast<ushort4*>(h2b + (size_t)gr * OUT_CH + tx * 4) = o;
        }
    }
}

// out[n](f32) = b + h[n]*dinv[n]^2 + sum_e h[rec.src]*rec.w*dinv[n]
template <int C>
__global__ __launch_bounds__(256) void k_gather(const unsigned short* __restrict__ h,
                                                const int* __restrict__ row_ptr,
                                                const int2* __restrict__ csr,
                                                const float* __restrict__ dinv,
                                                const float* __restrict__ b,
                                                float* __restrict__ out, int N) {
    constexpr int LPN = C / 4;
    const int tid  = blockIdx.x * blockDim.x + threadIdx.x;
    const int node = tid / LPN;
    const int lane = tid % LPN;
    if (node >= N) return;

    const float dn = dinv[node];
    float4 acc = reinterpret_cast<const float4*>(b)[lane];
    {
        const float w = dn * dn;  // self loop
        const ushort4 v = *reinterpret_cast<const ushort4*>(h + (size_t)node * C + lane * 4);
        acc.x = fmaf(bf2f(v.x), w, acc.x); acc.y = fmaf(bf2f(v.y), w, acc.y);
        acc.z = fmaf(bf2f(v.z), w, acc.z); acc.w = fmaf(bf2f(v.w), w, acc.w);
    }

    const int e1 = row_ptr[node + 1];
    int e = row_ptr[node];
    for (; e + 1 < e1; e += 2) {
        const int2 r0 = csr[e];
        const int2 r1 = csr[e + 1];
        const float w0 = __int_as_float(r0.y) * dn;
        const float w1 = __int_as_float(r1.y) * dn;
        const ushort4 v0 = *reinterpret_cast<const ushort4*>(h + (size_t)r0.x * C + lane * 4);
        const ushort4 v1 = *reinterpret_cast<const ushort4*>(h + (size_t)r1.x * C + lane * 4);
        acc.x = fmaf(bf2f(v0.x), w0, acc.x); acc.y = fmaf(bf2f(v0.y), w0, acc.y);
        acc.z = fmaf(bf2f(v0.z), w0, acc.z); acc.w = fmaf(bf2f(v0.w), w0, acc.w);
        acc.x = fmaf(bf2f(v1.x), w1, acc.x); acc.y = fmaf(bf2f(v1.y), w1, acc.y);
        acc.z = fmaf(bf2f(v1.z), w1, acc.z); acc.w = fmaf(bf2f(v1.w), w1, acc.w);
    }
    if (e < e1) {
        const int2 r0 = csr[e];
        const float w0 = __int_as_float(r0.y) * dn;
        const ushort4 v0 = *reinterpret_cast<const ushort4*>(h + (size_t)r0.x * C + lane * 4);
        acc.x = fmaf(bf2f(v0.x), w0, acc.x); acc.y = fmaf(bf2f(v0.y), w0, acc.y);
        acc.z = fmaf(bf2f(v0.z), w0, acc.z); acc.w = fmaf(bf2f(v0.w), w0, acc.w);
    }

    reinterpret_cast<float4*>(out + (size_t)node * C)[lane] = acc;
}

extern "C" void kernel_launch(void* const* d_in, const int* in_sizes, int n_in,
                              void* d_out, int out_size, void* d_ws, size_t ws_size,
                              hipStream_t stream) {
    const float* x  = (const float*)d_in[0];
    const int*   ei = (const int*)d_in[1];
    const float* W1 = (const float*)d_in[2];
    const float* b1 = (const float*)d_in[3];
    const float* W2 = (const float*)d_in[4];
    const float* b2 = (const float*)d_in[5];
    float* out = (float*)d_out;

    const int N = in_sizes[0] / IN_CH;   // 50000
    const int E = in_sizes[1] / 2;       // 600000
    const int NBLK = (N + SCAN_CHUNK - 1) / SCAN_CHUNK;   // 13

    char* wsb = (char*)d_ws;
    size_t off = 0;
    auto alloc = [&](size_t bytes) -> void* {
        void* p = wsb + off;
        off += (bytes + 255) & ~(size_t)255;
        return p;
    };
    int*   indeg    = (int*)alloc((size_t)N * sizeof(int));
    int*   partials = (int*)alloc(64 * sizeof(int));
    float* dinv     = (float*)alloc((size_t)N * sizeof(float));
    int*   row_ptr  = (int*)alloc(((size_t)N + 1) * sizeof(int));
    int2*  csr      = (int2*)alloc((size_t)E * sizeof(int2));
    unsigned short* h1b = (unsigned short*)alloc((size_t)N * HID * sizeof(unsigned short));
    unsigned short* h2b = (unsigned short*)alloc((size_t)N * OUT_CH * sizeof(unsigned short));
    int*   cursor   = indeg;   // indeg dead after k_scan1

    auto gs = [](long long n) { return (int)((n + 255) / 256); };

    k_init<<<64, 256, 0, stream>>>(indeg, N);
    k_count<<<gs(E), 256, 0, stream>>>(ei, indeg, E);
    k_scan1<<<NBLK, 256, 0, stream>>>(indeg, row_ptr, dinv, partials, N);
    k_scan3<<<NBLK, 256, 0, stream>>>(partials, row_ptr, cursor, N, NBLK);

    // layer 1 transform fused with CSR fill (independent work)
    const int gemmBlocks = (N + 63) / 64;        // 782
    const int fillBlocks = 512;
    k_gemm_fill<<<gemmBlocks + fillBlocks, 256, 0, stream>>>(
        x, W1, h1b, N, gemmBlocks, ei, dinv, cursor, csr, E);

    // gather1 + ReLU + gemm2 fused, tile-local
    k_gather_gemm2<<<(N + 63) / 64, 256, 0, stream>>>(
        h1b, row_ptr, csr, dinv, b1, W2, h2b, N);

    // final gather + bias -> out (f32)
    k_gather<OUT_CH><<<gs((long long)N * (OUT_CH / 4)), 256, 0, stream>>>(
        h2b, row_ptr, csr, dinv, b2, out, N);
}